// Round 3
// baseline (275.707 us; speedup 1.0000x reference)
//
#include <hip/hip_runtime.h>
#include <hip/hip_bf16.h>

// Effi_MVS: B=1, V=5, C=32, D=48, H=128, W=160, RATIO=8.
// Round 3: dtype resolved by evidence.
//   - Inputs fp32 (round-1 forced-bf16 NaN'd; round-2 fp32 sniff path didn't).
//   - Outputs fp32 (round-2 absmax 756 == "zero tail" signature of writing
//     bf16 into a fp32-sized buffer; reference returns float32).
// Structure: conv has 1 output channel -> contract C against the 27 conv
// weights inside the warp kernel (variance volume never hits HBM); the 3d
// conv then collapses to 27 shifted adds over the contracted WV volume.

#define NV 5
#define NC 32
#define ND 48
#define NH 128
#define NW 160
#define HW (NH * NW)
#define DHW (ND * HW)

typedef __attribute__((ext_vector_type(2))) float f32x2;

// ws layout (bytes)
#define OFF_M      0          // float M[4][12]   rot(9)+trans(3) per src view
#define OFF_WF     256        // float wf[32][28] conv weights fp32, padded
#define OFF_DEPTHF 4096       // float depthf[20480]
#define OFF_PRE    86016      // float pre[48*128*160]
#define OFF_WV     4018176    // bf16 WV[27][48*128*160]
// total = 57,102,336 bytes

// ---------------------------------------------------------------- K1: setup
__global__ void k_setup(const float* __restrict__ proj,
                        const float* __restrict__ wreg,
                        float* __restrict__ M, float* __restrict__ wf) {
  if (threadIdx.x != 0) return;
  double P[NV][2][4][4];
  for (int v = 0; v < NV; ++v)
    for (int m = 0; m < 2; ++m)
      for (int i = 0; i < 4; ++i)
        for (int j = 0; j < 4; ++j)
          P[v][m][i][j] = (double)proj[((v * 2 + m) * 4 + i) * 4 + j];
  // combine: top 3x4 = K @ E[:3,:4]
  double C[NV][4][4];
  for (int v = 0; v < NV; ++v) {
    for (int i = 0; i < 4; ++i)
      for (int j = 0; j < 4; ++j) C[v][i][j] = P[v][0][i][j];
    for (int i = 0; i < 3; ++i)
      for (int j = 0; j < 4; ++j) {
        double s = 0.0;
        for (int k = 0; k < 3; ++k) s += P[v][1][i][k] * P[v][0][k][j];
        C[v][i][j] = s;
      }
  }
  // invert C[0] (Gauss-Jordan, partial pivot, double)
  double a[4][8];
  for (int i = 0; i < 4; ++i)
    for (int j = 0; j < 4; ++j) { a[i][j] = C[0][i][j]; a[i][j + 4] = (i == j) ? 1.0 : 0.0; }
  for (int col = 0; col < 4; ++col) {
    int piv = col; double best = fabs(a[col][col]);
    for (int r = col + 1; r < 4; ++r) { double v = fabs(a[r][col]); if (v > best) { best = v; piv = r; } }
    if (piv != col)
      for (int j = 0; j < 8; ++j) { double t = a[col][j]; a[col][j] = a[piv][j]; a[piv][j] = t; }
    double pv = a[col][col];
    for (int j = 0; j < 8; ++j) a[col][j] /= pv;
    for (int r = 0; r < 4; ++r) if (r != col) {
      double f = a[r][col];
      for (int j = 0; j < 8; ++j) a[r][j] -= f * a[col][j];
    }
  }
  double inv[4][4];
  for (int i = 0; i < 4; ++i)
    for (int j = 0; j < 4; ++j) inv[i][j] = a[i][j + 4];
  // per src view: Pm = C[v] @ inv(ref)
  for (int v = 1; v < NV; ++v) {
    float* m = M + (v - 1) * 12;
    for (int i = 0; i < 3; ++i) {
      double r[4] = {0, 0, 0, 0};
      for (int k = 0; k < 4; ++k) {
        double cv = C[v][i][k];
        for (int j = 0; j < 4; ++j) r[j] += cv * inv[k][j];
      }
      m[i * 3 + 0] = (float)r[0]; m[i * 3 + 1] = (float)r[1]; m[i * 3 + 2] = (float)r[2];
      m[9 + i] = (float)r[3];
    }
  }
  for (int c = 0; c < NC; ++c) {
    for (int t = 0; t < 27; ++t) wf[c * 28 + t] = wreg[c * 27 + t];
    wf[c * 28 + 27] = 0.f;
  }
}

// ------------------------------------------- K2: warp + variance + contract
__global__ __launch_bounds__(256) void k_warpvar(
    const float* __restrict__ feat,    // [5][32][128][160]
    const float* __restrict__ depthv,  // [48]
    const float* __restrict__ M,       // [4][12]
    const float* __restrict__ wf,      // [32][28]
    __hip_bfloat16* __restrict__ WV)   // [27][48*128*160]
{
  int idx = blockIdx.x * 256 + threadIdx.x;
  int x = idx % NW;
  int t1 = idx / NW;
  int y = t1 % NH;
  int d = t1 / NH;
  float xf = (float)x, yf = (float)y;
  float df = depthv[d];

  int   cidx[16];
  float cw[16];
#pragma unroll
  for (int v = 0; v < 4; ++v) {
    const float* m = M + v * 12;
    float rx = m[0] * xf + m[1] * yf + m[2];
    float ry = m[3] * xf + m[4] * yf + m[5];
    float rz = m[6] * xf + m[7] * yf + m[8];
    float px = rx * df + m[9];
    float py = ry * df + m[10];
    float pz = rz * df + m[11];
    float gx = px / pz;
    float gy = py / pz;
    float x0 = floorf(gx), y0 = floorf(gy);
    float wx = gx - x0, wy = gy - y0;
    float cxs[2] = {x0, x0 + 1.f}, cys[2] = {y0, y0 + 1.f};
    float wxs[2] = {1.f - wx, wx}, wys[2] = {1.f - wy, wy};
#pragma unroll
    for (int cy = 0; cy < 2; ++cy)
#pragma unroll
      for (int cx = 0; cx < 2; ++cx) {
        float fx = cxs[cx], fy = cys[cy];
        bool valid = (fx >= 0.f) && (fx <= (float)(NW - 1)) &&
                     (fy >= 0.f) && (fy <= (float)(NH - 1));
        float fxc = fminf(fmaxf(fx, 0.f), (float)(NW - 1));
        float fyc = fminf(fmaxf(fy, 0.f), (float)(NH - 1));
        int xi = (int)fxc, yi = (int)fyc;
        cidx[v * 4 + cy * 2 + cx] = yi * NW + xi;
        cw[v * 4 + cy * 2 + cx] = wxs[cx] * wys[cy] * (valid ? 1.f : 0.f);
      }
  }

  int pix = y * NW + x;
  f32x2 wv[14];
#pragma unroll
  for (int u = 0; u < 14; ++u) wv[u] = (f32x2){0.f, 0.f};

#pragma unroll
  for (int c = 0; c < NC; ++c) {
    float f0 = feat[c * HW + pix];
    float vs = f0, vq = f0 * f0;
#pragma unroll
    for (int v = 0; v < 4; ++v) {
      const float* fv = feat + ((v + 1) * NC + c) * HW;
      float val = cw[v * 4 + 0] * fv[cidx[v * 4 + 0]]
                + cw[v * 4 + 1] * fv[cidx[v * 4 + 1]]
                + cw[v * 4 + 2] * fv[cidx[v * 4 + 2]]
                + cw[v * 4 + 3] * fv[cidx[v * 4 + 3]];
      vs += val;
      vq += val * val;
    }
    float var = vq * 0.2f - (vs * 0.2f) * (vs * 0.2f);
    const f32x2* wrow = (const f32x2*)(wf + c * 28);
    f32x2 vv; vv.x = var; vv.y = var;
#pragma unroll
    for (int u = 0; u < 14; ++u) wv[u] += wrow[u] * vv;
  }

#pragma unroll
  for (int u = 0; u < 14; ++u) {
    int t0 = 2 * u;
    WV[t0 * DHW + idx] = __float2bfloat16(wv[u].x);
    if (t0 + 1 < 27) WV[(t0 + 1) * DHW + idx] = __float2bfloat16(wv[u].y);
  }
}

// ------------------------------------------------- K3a: 27-tap gather (conv)
__global__ __launch_bounds__(256) void k_conv(const __hip_bfloat16* __restrict__ WV,
                                              float* __restrict__ pre) {
  int idx = blockIdx.x * 256 + threadIdx.x;
  int x = idx % NW;
  int t1 = idx / NW;
  int y = t1 % NH;
  int d = t1 / NH;
  float acc = 0.f;
#pragma unroll
  for (int dd = 0; dd < 3; ++dd) {
    int dp = d + dd - 1;
    bool dok = (dp >= 0) && (dp < ND);
    int dpc = min(max(dp, 0), ND - 1);
#pragma unroll
    for (int i = 0; i < 3; ++i) {
      int yp = y + i - 1;
      bool yok = (yp >= 0) && (yp < NH);
      int ypc = min(max(yp, 0), NH - 1);
#pragma unroll
      for (int j = 0; j < 3; ++j) {
        int xp = x + j - 1;
        bool xok = (xp >= 0) && (xp < NW);
        int xpc = min(max(xp, 0), NW - 1);
        int t = dd * 9 + i * 3 + j;
        float v = __bfloat162float(WV[t * DHW + dpc * HW + ypc * NW + xpc]);
        acc += (dok && yok && xok) ? v : 0.f;
      }
    }
  }
  pre[idx] = acc;
}

// ---------------------------------------- K3b: softmax over D + depth + conf
__global__ __launch_bounds__(256) void k_softmax(const float* __restrict__ pre,
                                                 const float* __restrict__ depthv,
                                                 float* __restrict__ depthf,
                                                 float* __restrict__ out_depth,
                                                 float* __restrict__ out_conf) {
  int p = blockIdx.x * 256 + threadIdx.x;
  float pr[ND];
  float m = -1e30f;
#pragma unroll
  for (int d = 0; d < ND; ++d) { pr[d] = pre[d * HW + p]; m = fmaxf(m, pr[d]); }
  float s = 0.f;
#pragma unroll
  for (int d = 0; d < ND; ++d) { pr[d] = expf(pr[d] - m); s += pr[d]; }
  float inv = 1.f / s;
  float dep = 0.f, ti = 0.f;
#pragma unroll
  for (int d = 0; d < ND; ++d) {
    float prob = pr[d] * inv;
    pr[d] = prob;
    dep += prob * depthv[d];
    ti += prob * (float)d;
  }
  int di = (int)ti;  // truncation toward zero, matches astype(int32)
  di = di < 0 ? 0 : (di > ND - 1 ? ND - 1 : di);
  float conf = 0.f;
#pragma unroll
  for (int d = 0; d < ND; ++d)
    conf += (d >= di - 1 && d <= di + 2) ? pr[d] : 0.f;
  depthf[p] = dep;
  out_depth[p] = dep;
  out_conf[p] = conf;
}

// -------------------------------------------------- K4: convex upsample (x8)
__global__ __launch_bounds__(256) void k_upsample(const float* __restrict__ mask,
                                                  const float* __restrict__ depthf,
                                                  float* __restrict__ out) {
  int idx = blockIdx.x * 256 + threadIdx.x;  // row-major over (1024, 1280)
  int fx = idx % (NW * 8);
  int fy = idx / (NW * 8);
  int x = fx >> 3, dx = fx & 7;
  int y = fy >> 3, dy = fy & 7;
  float mv[9];
  float mmax = -1e30f;
#pragma unroll
  for (int k = 0; k < 9; ++k) {
    mv[k] = mask[((k * 8 + dy) * 8 + dx) * HW + y * NW + x];
    mmax = fmaxf(mmax, mv[k]);
  }
  float s = 0.f;
#pragma unroll
  for (int k = 0; k < 9; ++k) { mv[k] = expf(mv[k] - mmax); s += mv[k]; }
  float acc = 0.f;
#pragma unroll
  for (int k = 0; k < 9; ++k) {
    int ky = y + k / 3 - 1;
    int kx = x + k % 3 - 1;
    bool ok = (ky >= 0) && (ky < NH) && (kx >= 0) && (kx < NW);
    int kyc = min(max(ky, 0), NH - 1);
    int kxc = min(max(kx, 0), NW - 1);
    float dv = depthf[kyc * NW + kxc];
    acc += mv[k] * (ok ? dv : 0.f);
  }
  out[idx] = acc / s;
}

// ---------------------------------------------------------------- launcher
extern "C" void kernel_launch(void* const* d_in, const int* in_sizes, int n_in,
                              void* d_out, int out_size, void* d_ws, size_t ws_size,
                              hipStream_t stream) {
  const float* feat   = (const float*)d_in[0];  // 3,276,800
  const float* proj   = (const float*)d_in[1];  // 160
  const float* depthv = (const float*)d_in[2];  // 48
  const float* mask   = (const float*)d_in[3];  // 11,796,480
  const float* wreg   = (const float*)d_in[4];  // 864

  char* ws = (char*)d_ws;
  float* M       = (float*)(ws + OFF_M);
  float* wf      = (float*)(ws + OFF_WF);
  float* depthf  = (float*)(ws + OFF_DEPTHF);
  float* pre     = (float*)(ws + OFF_PRE);
  __hip_bfloat16* WV = (__hip_bfloat16*)(ws + OFF_WV);

  float* out = (float*)d_out;                     // fp32 outputs
  float* out_depth = out + (NH * 8) * (NW * 8);   // after 1,310,720 floats
  float* out_conf  = out_depth + HW;

  k_setup<<<1, 64, 0, stream>>>(proj, wreg, M, wf);
  k_warpvar<<<DHW / 256, 256, 0, stream>>>(feat, depthv, M, wf, WV);
  k_conv<<<DHW / 256, 256, 0, stream>>>(WV, pre);
  k_softmax<<<HW / 256, 256, 0, stream>>>(pre, depthv, depthf, out_depth, out_conf);
  k_upsample<<<(NH * 8 * NW * 8) / 256, 256, 0, stream>>>(mask, depthf, out);
}